// Round 1
// baseline (1321.522 us; speedup 1.0000x reference)
//
#include <hip/hip_runtime.h>

// Problem constants
// B=2, S=2048, E=512, H=8, D=64, MAX_SEQ=2048
// out0: (2,2048,512) = 2,097,152 floats at d_out
// attn: (2,8,2048,2048) = 67,108,864 floats at d_out + 2,097,152

// ---------------------------------------------------------------------------
// K1/K5: C(4096x512) = A(4096x512) @ W(512x512) + bias
// layout 0: row-major out.  layout 1: BHSD out (b,h,s,d) for q/k/v.
// ---------------------------------------------------------------------------
__global__ __launch_bounds__(256) void gemm_proj(const float* __restrict__ A,
                                                 const float* __restrict__ W,
                                                 const float* __restrict__ bias,
                                                 float* __restrict__ out,
                                                 int layout)
{
    __shared__ float As[16][68];   // [k][r]
    __shared__ float Ws[16][68];   // [k][c]
    const int t  = threadIdx.x;
    const int r0 = blockIdx.y << 6;
    const int c0 = blockIdx.x << 6;
    const int tr = t >> 4, tc = t & 15;

    float acc[4][4];
#pragma unroll
    for (int i = 0; i < 4; ++i)
#pragma unroll
        for (int j = 0; j < 4; ++j) acc[i][j] = 0.f;

    const int arow = t >> 2, akq = (t & 3) << 2;
    const int wkr  = t >> 4, wcc = (t & 15) << 2;

    for (int k0 = 0; k0 < 512; k0 += 16) {
        float4 a4 = *(const float4*)&A[(r0 + arow) * 512 + k0 + akq];
        As[akq + 0][arow] = a4.x;
        As[akq + 1][arow] = a4.y;
        As[akq + 2][arow] = a4.z;
        As[akq + 3][arow] = a4.w;
        *(float4*)&Ws[wkr][wcc] = *(const float4*)&W[(k0 + wkr) * 512 + c0 + wcc];
        __syncthreads();
#pragma unroll
        for (int kk = 0; kk < 16; ++kk) {
            float4 a = *(float4*)&As[kk][tr << 2];
            float4 b = *(float4*)&Ws[kk][tc << 2];
            acc[0][0] += a.x * b.x; acc[0][1] += a.x * b.y; acc[0][2] += a.x * b.z; acc[0][3] += a.x * b.w;
            acc[1][0] += a.y * b.x; acc[1][1] += a.y * b.y; acc[1][2] += a.y * b.z; acc[1][3] += a.y * b.w;
            acc[2][0] += a.z * b.x; acc[2][1] += a.z * b.y; acc[2][2] += a.z * b.z; acc[2][3] += a.z * b.w;
            acc[3][0] += a.w * b.x; acc[3][1] += a.w * b.y; acc[3][2] += a.w * b.z; acc[3][3] += a.w * b.w;
        }
        __syncthreads();
    }

    float4 bb = *(const float4*)&bias[c0 + (tc << 2)];
#pragma unroll
    for (int i = 0; i < 4; ++i) {
        int r = r0 + (tr << 2) + i;
        float4 val = make_float4(acc[i][0] + bb.x, acc[i][1] + bb.y,
                                 acc[i][2] + bb.z, acc[i][3] + bb.w);
        if (layout == 0) {
            *(float4*)&out[r * 512 + c0 + (tc << 2)] = val;
        } else {
            int b = r >> 11, s = r & 2047;
            int h = c0 >> 6;
            *(float4*)&out[(((b << 3) + h) * 2048 + s) * 64 + (tc << 2)] = val;
        }
    }
}

// ---------------------------------------------------------------------------
// K2: raw logits = QK^T + masked relative term, per 16x128 tile.
//   rel_scores[i][j] = (j<=i) ? q[i] . rel[2047-i+j] : 0
// Writes UNSCALED (scale 1/8 folded into softmax).
// ---------------------------------------------------------------------------
__global__ __launch_bounds__(256) void logits_k(const float* __restrict__ q,
                                                const float* __restrict__ k,
                                                const float* __restrict__ rel,
                                                float* __restrict__ attn)
{
    __shared__ float q_s[16][64];
    __shared__ float k_t[64][129];    // [d][jj] transposed, lane-consecutive reads
    __shared__ float rel_t[64][145];  // [d][c] band, c = m - m0, 143 rows

    const int t  = threadIdx.x;
    const int j0 = blockIdx.x << 7;   // key tile start (128 wide)
    const int i0 = blockIdx.y << 4;   // query tile start (16 tall)
    const int bh = blockIdx.z;

    const float* qb = q + (bh * 2048 + i0) * 64;
    const float* kb = k + (bh * 2048 + j0) * 64;

    // stage q (16x64)
    {
        int qi = t >> 4, qd = (t & 15) << 2;
        *(float4*)&q_s[qi][qd] = *(const float4*)&qb[qi * 64 + qd];
    }
    // stage k transposed (128x64 -> [d][jj])
    {
        int d4 = (t & 15) << 2;
#pragma unroll
        for (int it = 0; it < 8; ++it) {
            int jj = (t >> 4) + (it << 4);
            float4 v = *(const float4*)&kb[jj * 64 + d4];
            k_t[d4 + 0][jj] = v.x;
            k_t[d4 + 1][jj] = v.y;
            k_t[d4 + 2][jj] = v.z;
            k_t[d4 + 3][jj] = v.w;
        }
    }
    const bool anyRel = (j0 <= i0 + 15);
    const int  m0     = j0 + 2032 - i0;  // = 2047 - (i0+15) + j0, always >= 0
    if (anyRel) {
        int d4 = (t & 15) << 2;
        for (int it = 0; it < 9; ++it) {
            int rr = (t >> 4) + (it << 4);
            if (rr < 143) {
                int m = m0 + rr;
                if (m > 2047) m = 2047;  // clamped rows only feed masked pairs
                float4 v = *(const float4*)&rel[m * 64 + d4];
                rel_t[d4 + 0][rr] = v.x;
                rel_t[d4 + 1][rr] = v.y;
                rel_t[d4 + 2][rr] = v.z;
                rel_t[d4 + 3][rr] = v.w;
            }
        }
    }
    __syncthreads();

    const int jj = t & 127;
    const int hb = (t >> 7) << 3;  // 0 for waves 0-1, 8 for waves 2-3

    float acc[8];
#pragma unroll
    for (int ii = 0; ii < 8; ++ii) acc[ii] = 0.f;

    // QK^T part
#pragma unroll
    for (int d4 = 0; d4 < 64; d4 += 4) {
        float kv0 = k_t[d4 + 0][jj];
        float kv1 = k_t[d4 + 1][jj];
        float kv2 = k_t[d4 + 2][jj];
        float kv3 = k_t[d4 + 3][jj];
#pragma unroll
        for (int ii = 0; ii < 8; ++ii) {
            float4 q4 = *(float4*)&q_s[hb + ii][d4];
            acc[ii] += q4.x * kv0 + q4.y * kv1 + q4.z * kv2 + q4.w * kv3;
        }
    }

    // relative part
    if (anyRel) {
#pragma unroll
        for (int ii = 0; ii < 8; ++ii) {
            int irow = hb + ii;               // 0..15
            int c    = jj + 15 - irow;        // 0..142, band column
            bool valid = (j0 + jj) <= (i0 + irow);
            float r = 0.f;
#pragma unroll
            for (int d4 = 0; d4 < 64; d4 += 4) {
                float4 q4 = *(float4*)&q_s[irow][d4];
                r += q4.x * rel_t[d4 + 0][c] + q4.y * rel_t[d4 + 1][c]
                   + q4.z * rel_t[d4 + 2][c] + q4.w * rel_t[d4 + 3][c];
            }
            acc[ii] += valid ? r : 0.f;
        }
    }

    // store raw logits (coalesced per row)
#pragma unroll
    for (int ii = 0; ii < 8; ++ii) {
        int i = i0 + hb + ii;
        attn[(size_t)(bh * 2048 + i) * 2048 + j0 + jj] = acc[ii];
    }
}

// ---------------------------------------------------------------------------
// K3: in-place row softmax over 2048 cols, one wave per row.
//   p = exp((raw - max)*0.125) / sum
// ---------------------------------------------------------------------------
__global__ __launch_bounds__(256) void softmax_k(float* __restrict__ attn)
{
    const int t    = threadIdx.x;
    const int lane = t & 63;
    const int w    = t >> 6;
    const int row  = (blockIdx.x << 2) + w;  // 0..32767
    float* p = attn + (size_t)row * 2048;

    float v[32];
#pragma unroll
    for (int c = 0; c < 8; ++c) {
        float4 x = *(const float4*)&p[(lane + (c << 6)) << 2];
        v[c * 4 + 0] = x.x; v[c * 4 + 1] = x.y; v[c * 4 + 2] = x.z; v[c * 4 + 3] = x.w;
    }
    float m = v[0];
#pragma unroll
    for (int i = 1; i < 32; ++i) m = fmaxf(m, v[i]);
#pragma unroll
    for (int off = 1; off < 64; off <<= 1) m = fmaxf(m, __shfl_xor(m, off, 64));

    float s = 0.f;
#pragma unroll
    for (int i = 0; i < 32; ++i) {
        float e = __expf((v[i] - m) * 0.125f);
        v[i] = e;
        s += e;
    }
#pragma unroll
    for (int off = 1; off < 64; off <<= 1) s += __shfl_xor(s, off, 64);

    float r = 1.0f / s;
#pragma unroll
    for (int c = 0; c < 8; ++c) {
        float4 x = make_float4(v[c * 4 + 0] * r, v[c * 4 + 1] * r,
                               v[c * 4 + 2] * r, v[c * 4 + 3] * r);
        *(float4*)&p[(lane + (c << 6)) << 2] = x;
    }
}

// ---------------------------------------------------------------------------
// K4: out = attn @ v  per (bh, 16-row tile); writes merged (B,S,512) layout.
// ---------------------------------------------------------------------------
__global__ __launch_bounds__(256) void pv_k(const float* __restrict__ attn,
                                            const float* __restrict__ v,
                                            float* __restrict__ merged)
{
    __shared__ float p_s[16][264];
    const int t  = threadIdx.x;
    const int g  = t >> 6;        // wave id 0..3
    const int d  = t & 63;
    const int i0 = blockIdx.x << 4;
    const int bh = blockIdx.y;
    const int b  = bh >> 3, h = bh & 7;

    const float* ab = attn + (size_t)(bh * 2048 + i0) * 2048;
    const float* vb = v + (size_t)bh * 2048 * 64;

    float acc[4] = {0.f, 0.f, 0.f, 0.f};
    const int si = t >> 4, sj = t & 15;

    for (int j0 = 0; j0 < 2048; j0 += 256) {
        __syncthreads();  // previous compute done before overwriting p_s
#pragma unroll
        for (int mm = 0; mm < 4; ++mm) {
            int jj4 = sj + (mm << 4);
            *(float4*)&p_s[si][jj4 << 2] = *(const float4*)&ab[si * 2048 + j0 + (jj4 << 2)];
        }
        __syncthreads();
#pragma unroll 8
        for (int jj4 = 0; jj4 < 64; ++jj4) {
            float4 p0 = *(float4*)&p_s[g     ][jj4 << 2];
            float4 p1 = *(float4*)&p_s[g + 4 ][jj4 << 2];
            float4 p2 = *(float4*)&p_s[g + 8 ][jj4 << 2];
            float4 p3 = *(float4*)&p_s[g + 12][jj4 << 2];
            int j = j0 + (jj4 << 2);
            float v0 = vb[(j + 0) * 64 + d];
            float v1 = vb[(j + 1) * 64 + d];
            float v2 = vb[(j + 2) * 64 + d];
            float v3 = vb[(j + 3) * 64 + d];
            acc[0] += p0.x * v0 + p0.y * v1 + p0.z * v2 + p0.w * v3;
            acc[1] += p1.x * v0 + p1.y * v1 + p1.z * v2 + p1.w * v3;
            acc[2] += p2.x * v0 + p2.y * v1 + p2.z * v2 + p2.w * v3;
            acc[3] += p3.x * v0 + p3.y * v1 + p3.z * v2 + p3.w * v3;
        }
    }
#pragma unroll
    for (int rr = 0; rr < 4; ++rr) {
        int srow = i0 + g + (rr << 2);
        merged[(size_t)(b * 2048 + srow) * 512 + (h << 6) + d] = acc[rr];
    }
}

// ---------------------------------------------------------------------------
extern "C" void kernel_launch(void* const* d_in, const int* in_sizes, int n_in,
                              void* d_out, int out_size, void* d_ws, size_t ws_size,
                              hipStream_t stream)
{
    const float* q_in = (const float*)d_in[0];
    const float* k_in = (const float*)d_in[1];
    const float* v_in = (const float*)d_in[2];
    const float* Wq   = (const float*)d_in[3];
    const float* bq   = (const float*)d_in[4];
    const float* Wk   = (const float*)d_in[5];
    const float* bk   = (const float*)d_in[6];
    const float* Wv   = (const float*)d_in[7];
    const float* bv   = (const float*)d_in[8];
    const float* Wo   = (const float*)d_in[9];
    const float* bo   = (const float*)d_in[10];
    const float* rel  = (const float*)d_in[11];

    float* out0 = (float*)d_out;
    float* attn = out0 + 2097152;      // (2,8,2048,2048)

    float* ws = (float*)d_ws;
    float* qW = ws;                    // (B,H,S,D) each 2,097,152 floats
    float* kW = qW + 2097152;
    float* vW = kW + 2097152;
    float* mW = vW + 2097152;          // merged (B,S,512)

    dim3 gProj(8, 64);                 // 512-col x 4096-row in 64x64 tiles
    gemm_proj<<<gProj, 256, 0, stream>>>(q_in, Wq, bq, qW, 1);
    gemm_proj<<<gProj, 256, 0, stream>>>(k_in, Wk, bk, kW, 1);
    gemm_proj<<<gProj, 256, 0, stream>>>(v_in, Wv, bv, vW, 1);

    logits_k<<<dim3(16, 128, 16), 256, 0, stream>>>(qW, kW, rel, attn);
    softmax_k<<<8192, 256, 0, stream>>>(attn);
    pv_k<<<dim3(128, 16), 256, 0, stream>>>(attn, vW, mW);

    gemm_proj<<<gProj, 256, 0, stream>>>(mW, Wo, bo, out0, 0);
}

// Round 2
// 836.364 us; speedup vs baseline: 1.5801x; 1.5801x over previous
//
#include <hip/hip_runtime.h>

// B=2, S=2048, E=512, H=8, D=64, MAX_SEQ=2048
// out0: (2,2048,512) floats at d_out;  attn: (2,8,2048,2048) at d_out+2097152

typedef __attribute__((ext_vector_type(4))) float f32x4;
typedef __attribute__((ext_vector_type(8))) short short8;

__device__ inline unsigned short f2bf(float x) {             // RTN-even fp32->bf16
    unsigned u = __float_as_uint(x);
    unsigned r = (u + 0x7fffu + ((u >> 16) & 1u)) >> 16;
    return (unsigned short)r;
}
__device__ inline float bf2f(unsigned short h) {
    return __uint_as_float(((unsigned)h) << 16);
}
// LDS swizzle for [rows][64] bf16 tiles (128 B rows): spread 8 rows over 16B slots
__device__ inline int swz(int row, int bytecol) {
    return (row << 7) + (bytecol ^ ((row & 7) << 4));
}

// ---------------------------------------------------------------------------
// K1/K5: C(4096x512) = A(4096x512) @ W(512x512) + bias (fp32 vector GEMM)
// ---------------------------------------------------------------------------
__global__ __launch_bounds__(256) void gemm_proj(const float* __restrict__ A,
                                                 const float* __restrict__ W,
                                                 const float* __restrict__ bias,
                                                 float* __restrict__ out,
                                                 int layout)
{
    __shared__ float As[16][68];
    __shared__ float Ws[16][68];
    const int t  = threadIdx.x;
    const int r0 = blockIdx.y << 6;
    const int c0 = blockIdx.x << 6;
    const int tr = t >> 4, tc = t & 15;

    float acc[4][4];
#pragma unroll
    for (int i = 0; i < 4; ++i)
#pragma unroll
        for (int j = 0; j < 4; ++j) acc[i][j] = 0.f;

    const int arow = t >> 2, akq = (t & 3) << 2;
    const int wkr  = t >> 4, wcc = (t & 15) << 2;

    for (int k0 = 0; k0 < 512; k0 += 16) {
        float4 a4 = *(const float4*)&A[(r0 + arow) * 512 + k0 + akq];
        As[akq + 0][arow] = a4.x;
        As[akq + 1][arow] = a4.y;
        As[akq + 2][arow] = a4.z;
        As[akq + 3][arow] = a4.w;
        *(float4*)&Ws[wkr][wcc] = *(const float4*)&W[(k0 + wkr) * 512 + c0 + wcc];
        __syncthreads();
#pragma unroll
        for (int kk = 0; kk < 16; ++kk) {
            float4 a = *(float4*)&As[kk][tr << 2];
            float4 b = *(float4*)&Ws[kk][tc << 2];
            acc[0][0] += a.x * b.x; acc[0][1] += a.x * b.y; acc[0][2] += a.x * b.z; acc[0][3] += a.x * b.w;
            acc[1][0] += a.y * b.x; acc[1][1] += a.y * b.y; acc[1][2] += a.y * b.z; acc[1][3] += a.y * b.w;
            acc[2][0] += a.z * b.x; acc[2][1] += a.z * b.y; acc[2][2] += a.z * b.z; acc[2][3] += a.z * b.w;
            acc[3][0] += a.w * b.x; acc[3][1] += a.w * b.y; acc[3][2] += a.w * b.z; acc[3][3] += a.w * b.w;
        }
        __syncthreads();
    }

    float4 bb = *(const float4*)&bias[c0 + (tc << 2)];
#pragma unroll
    for (int i = 0; i < 4; ++i) {
        int r = r0 + (tr << 2) + i;
        float4 val = make_float4(acc[i][0] + bb.x, acc[i][1] + bb.y,
                                 acc[i][2] + bb.z, acc[i][3] + bb.w);
        if (layout == 0) {
            *(float4*)&out[r * 512 + c0 + (tc << 2)] = val;
        } else {
            int b = r >> 11, s = r & 2047;
            int h = c0 >> 6;
            *(float4*)&out[(((b << 3) + h) * 2048 + s) * 64 + (tc << 2)] = val;
        }
    }
}

// ---------------------------------------------------------------------------
// K2: raw logits = QK^T (split-bf16, 3 MFMA terms) + masked rel (1 MFMA term)
// Tile: 32 rows x 128 cols, 4 waves (2x2), 16x16x32 bf16 MFMA.
// rel handled as band matmul P[i][c] = q[i].rel[m0+c] then skew-gather.
// Writes UNSCALED logits (softmax applies 0.125).
// ---------------------------------------------------------------------------
__global__ __launch_bounds__(256) void logits_mfma(const float* __restrict__ q,
                                                   const float* __restrict__ k,
                                                   const float* __restrict__ rel,
                                                   float* __restrict__ attn)
{
    __shared__ char smem[61440];
    char* qh = smem;            // [32][64] bf16 hi, swizzled (4 KB)
    char* ql = smem + 4096;     // [32][64] bf16 lo
    char* kh = smem + 8192;     // [128][64] bf16 hi (16 KB)
    char* kl = smem + 24576;    // [128][64] bf16 lo
    char* rh = smem + 40960;    // [160][64] bf16 hi (20 KB)
    float* P = (float*)(smem + 8192);   // [32][162] fp32, overlays kh/kl after QK

    const int t  = threadIdx.x;
    const int j0 = blockIdx.x << 7;
    const int i0 = blockIdx.y << 5;
    const int bh = blockIdx.z;
    const bool anyRel = (j0 <= i0 + 31);
    const int m0 = 2016 + j0 - i0;     // band start: m = m0 + c = 2047 - i + j

    // ---- stage Q (32x64) -> hi/lo bf16
    {
        int row = t >> 3, d0 = (t & 7) << 3;
        const float* src = q + ((size_t)(bh * 2048 + i0 + row)) * 64 + d0;
#pragma unroll
        for (int i2 = 0; i2 < 2; ++i2) {
            float4 v = *(const float4*)(src + i2 * 4);
            unsigned short h0 = f2bf(v.x), h1 = f2bf(v.y), h2 = f2bf(v.z), h3 = f2bf(v.w);
            unsigned short l0 = f2bf(v.x - bf2f(h0)), l1 = f2bf(v.y - bf2f(h1));
            unsigned short l2 = f2bf(v.z - bf2f(h2)), l3 = f2bf(v.w - bf2f(h3));
            int phys = swz(row, (d0 + i2 * 4) * 2);
            *(uint2*)(qh + phys) = make_uint2(((unsigned)h1 << 16) | h0, ((unsigned)h3 << 16) | h2);
            *(uint2*)(ql + phys) = make_uint2(((unsigned)l1 << 16) | l0, ((unsigned)l3 << 16) | l2);
        }
    }
    // ---- stage K-tile (128x64) -> hi/lo bf16
    {
        int row = t >> 1, d0 = (t & 1) << 5;
        const float* src = k + ((size_t)(bh * 2048 + j0 + row)) * 64 + d0;
#pragma unroll
        for (int i4 = 0; i4 < 8; ++i4) {
            float4 v = *(const float4*)(src + i4 * 4);
            unsigned short h0 = f2bf(v.x), h1 = f2bf(v.y), h2 = f2bf(v.z), h3 = f2bf(v.w);
            unsigned short l0 = f2bf(v.x - bf2f(h0)), l1 = f2bf(v.y - bf2f(h1));
            unsigned short l2 = f2bf(v.z - bf2f(h2)), l3 = f2bf(v.w - bf2f(h3));
            int phys = swz(row, (d0 + i4 * 4) * 2);
            *(uint2*)(kh + phys) = make_uint2(((unsigned)h1 << 16) | h0, ((unsigned)h3 << 16) | h2);
            *(uint2*)(kl + phys) = make_uint2(((unsigned)l1 << 16) | l0, ((unsigned)l3 << 16) | l2);
        }
    }
    // ---- stage rel band (160x64) -> hi bf16 only (rel values ~0.04: lo negligible)
    if (anyRel) {
        int d0 = (t & 1) << 5;
        for (int rr = t >> 1; rr < 160; rr += 128) {
            int m = m0 + rr;
            if (m > 2047) m = 2047;   // clamped rows feed only masked elements
            const float* src = rel + m * 64 + d0;
#pragma unroll
            for (int i4 = 0; i4 < 8; ++i4) {
                float4 v = *(const float4*)(src + i4 * 4);
                unsigned short h0 = f2bf(v.x), h1 = f2bf(v.y), h2 = f2bf(v.z), h3 = f2bf(v.w);
                *(uint2*)(rh + swz(rr, (d0 + i4 * 4) * 2)) =
                    make_uint2(((unsigned)h1 << 16) | h0, ((unsigned)h3 << 16) | h2);
            }
        }
    }
    __syncthreads();

    // ---- MFMA phase
    const int lane = t & 63, w = t >> 6;
    const int wr = w >> 1, wc = w & 1;          // wave grid 2x2: rows 16*wr, cols 64*wc
    const int lr = lane & 15, kg = lane >> 4;   // frag: row/col = lr, k = 8*kg + e

    short8 aH0 = *(const short8*)(qh + swz(16 * wr + lr, kg * 16));
    short8 aH1 = *(const short8*)(qh + swz(16 * wr + lr, 64 + kg * 16));
    short8 aL0 = *(const short8*)(ql + swz(16 * wr + lr, kg * 16));
    short8 aL1 = *(const short8*)(ql + swz(16 * wr + lr, 64 + kg * 16));

    f32x4 acc[4];
#pragma unroll
    for (int f = 0; f < 4; ++f) {
        int row = 64 * wc + 16 * f + lr;
        short8 bH0 = *(const short8*)(kh + swz(row, kg * 16));
        short8 bH1 = *(const short8*)(kh + swz(row, 64 + kg * 16));
        short8 bL0 = *(const short8*)(kl + swz(row, kg * 16));
        short8 bL1 = *(const short8*)(kl + swz(row, 64 + kg * 16));
        f32x4 c = {0.f, 0.f, 0.f, 0.f};
        c = __builtin_amdgcn_mfma_f32_16x16x32_bf16(aH0, bH0, c, 0, 0, 0);
        c = __builtin_amdgcn_mfma_f32_16x16x32_bf16(aH1, bH1, c, 0, 0, 0);
        c = __builtin_amdgcn_mfma_f32_16x16x32_bf16(aH0, bL0, c, 0, 0, 0);
        c = __builtin_amdgcn_mfma_f32_16x16x32_bf16(aH1, bL1, c, 0, 0, 0);
        c = __builtin_amdgcn_mfma_f32_16x16x32_bf16(aL0, bH0, c, 0, 0, 0);
        c = __builtin_amdgcn_mfma_f32_16x16x32_bf16(aL1, bH1, c, 0, 0, 0);
        acc[f] = c;
    }

    if (anyRel) {
        f32x4 pr[5];
#pragma unroll
        for (int ff = 0; ff < 5; ++ff) {
            int bandf = wc + 2 * ff;            // 10 band frags split across wc
            int row = 16 * bandf + lr;
            short8 rb0 = *(const short8*)(rh + swz(row, kg * 16));
            short8 rb1 = *(const short8*)(rh + swz(row, 64 + kg * 16));
            f32x4 c = {0.f, 0.f, 0.f, 0.f};
            c = __builtin_amdgcn_mfma_f32_16x16x32_bf16(aH0, rb0, c, 0, 0, 0);
            c = __builtin_amdgcn_mfma_f32_16x16x32_bf16(aH1, rb1, c, 0, 0, 0);
            pr[ff] = c;
        }
        __syncthreads();   // all waves done reading kh/kl -> safe to overlay P
#pragma unroll
        for (int ff = 0; ff < 5; ++ff) {
            int bandf = wc + 2 * ff;
#pragma unroll
            for (int e = 0; e < 4; ++e)
                P[(16 * wr + 4 * kg + e) * 162 + 16 * bandf + lr] = pr[ff][e];
        }
        __syncthreads();
    }

    // ---- epilogue: skew-gather rel band, write raw logits
    const size_t obase = ((size_t)bh * 2048 + i0) * 2048 + j0;
#pragma unroll
    for (int f = 0; f < 4; ++f) {
        int cj = 64 * wc + 16 * f + lr;
#pragma unroll
        for (int e = 0; e < 4; ++e) {
            int r = 16 * wr + 4 * kg + e;
            float val = acc[f][e];
            if (anyRel && (j0 + cj) <= (i0 + r))
                val += P[r * 162 + cj + 31 - r];   // band col c = cj + 31 - r
            attn[obase + (size_t)r * 2048 + cj] = val;
        }
    }
}

// ---------------------------------------------------------------------------
// K3: in-place row softmax over 2048 cols, one wave per row.
// ---------------------------------------------------------------------------
__global__ __launch_bounds__(256) void softmax_k(float* __restrict__ attn)
{
    const int t    = threadIdx.x;
    const int lane = t & 63;
    const int w    = t >> 6;
    const int row  = (blockIdx.x << 2) + w;
    float* p = attn + (size_t)row * 2048;

    float v[32];
#pragma unroll
    for (int c = 0; c < 8; ++c) {
        float4 x = *(const float4*)&p[(lane + (c << 6)) << 2];
        v[c * 4 + 0] = x.x; v[c * 4 + 1] = x.y; v[c * 4 + 2] = x.z; v[c * 4 + 3] = x.w;
    }
    float m = v[0];
#pragma unroll
    for (int i = 1; i < 32; ++i) m = fmaxf(m, v[i]);
#pragma unroll
    for (int off = 1; off < 64; off <<= 1) m = fmaxf(m, __shfl_xor(m, off, 64));

    float s = 0.f;
#pragma unroll
    for (int i = 0; i < 32; ++i) {
        float e = __expf((v[i] - m) * 0.125f);
        v[i] = e;
        s += e;
    }
#pragma unroll
    for (int off = 1; off < 64; off <<= 1) s += __shfl_xor(s, off, 64);

    float r = 1.0f / s;
#pragma unroll
    for (int c = 0; c < 8; ++c) {
        float4 x = make_float4(v[c * 4 + 0] * r, v[c * 4 + 1] * r,
                               v[c * 4 + 2] * r, v[c * 4 + 3] * r);
        *(float4*)&p[(lane + (c << 6)) << 2] = x;
    }
}

// ---------------------------------------------------------------------------
// K4: out = attn @ v  per (bh, 16-row tile); writes merged (B,S,512) layout.
// ---------------------------------------------------------------------------
__global__ __launch_bounds__(256) void pv_k(const float* __restrict__ attn,
                                            const float* __restrict__ v,
                                            float* __restrict__ merged)
{
    __shared__ float p_s[16][264];
    const int t  = threadIdx.x;
    const int g  = t >> 6;
    const int d  = t & 63;
    const int i0 = blockIdx.x << 4;
    const int bh = blockIdx.y;
    const int b  = bh >> 3, h = bh & 7;

    const float* ab = attn + (size_t)(bh * 2048 + i0) * 2048;
    const float* vb = v + (size_t)bh * 2048 * 64;

    float acc[4] = {0.f, 0.f, 0.f, 0.f};
    const int si = t >> 4, sj = t & 15;

    for (int j0 = 0; j0 < 2048; j0 += 256) {
        __syncthreads();
#pragma unroll
        for (int mm = 0; mm < 4; ++mm) {
            int jj4 = sj + (mm << 4);
            *(float4*)&p_s[si][jj4 << 2] = *(const float4*)&ab[si * 2048 + j0 + (jj4 << 2)];
        }
        __syncthreads();
#pragma unroll 8
        for (int jj4 = 0; jj4 < 64; ++jj4) {
            float4 p0 = *(float4*)&p_s[g     ][jj4 << 2];
            float4 p1 = *(float4*)&p_s[g + 4 ][jj4 << 2];
            float4 p2 = *(float4*)&p_s[g + 8 ][jj4 << 2];
            float4 p3 = *(float4*)&p_s[g + 12][jj4 << 2];
            int j = j0 + (jj4 << 2);
            float v0 = vb[(j + 0) * 64 + d];
            float v1 = vb[(j + 1) * 64 + d];
            float v2 = vb[(j + 2) * 64 + d];
            float v3 = vb[(j + 3) * 64 + d];
            acc[0] += p0.x * v0 + p0.y * v1 + p0.z * v2 + p0.w * v3;
            acc[1] += p1.x * v0 + p1.y * v1 + p1.z * v2 + p1.w * v3;
            acc[2] += p2.x * v0 + p2.y * v1 + p2.z * v2 + p2.w * v3;
            acc[3] += p3.x * v0 + p3.y * v1 + p3.z * v2 + p3.w * v3;
        }
    }
#pragma unroll
    for (int rr = 0; rr < 4; ++rr) {
        int srow = i0 + g + (rr << 2);
        merged[(size_t)(b * 2048 + srow) * 512 + (h << 6) + d] = acc[rr];
    }
}

// ---------------------------------------------------------------------------
extern "C" void kernel_launch(void* const* d_in, const int* in_sizes, int n_in,
                              void* d_out, int out_size, void* d_ws, size_t ws_size,
                              hipStream_t stream)
{
    const float* q_in = (const float*)d_in[0];
    const float* k_in = (const float*)d_in[1];
    const float* v_in = (const float*)d_in[2];
    const float* Wq   = (const float*)d_in[3];
    const float* bq   = (const float*)d_in[4];
    const float* Wk   = (const float*)d_in[5];
    const float* bk   = (const float*)d_in[6];
    const float* Wv   = (const float*)d_in[7];
    const float* bv   = (const float*)d_in[8];
    const float* Wo   = (const float*)d_in[9];
    const float* bo   = (const float*)d_in[10];
    const float* rel  = (const float*)d_in[11];

    float* out0 = (float*)d_out;
    float* attn = out0 + 2097152;

    float* ws = (float*)d_ws;
    float* qW = ws;
    float* kW = qW + 2097152;
    float* vW = kW + 2097152;
    float* mW = vW + 2097152;

    dim3 gProj(8, 64);
    gemm_proj<<<gProj, 256, 0, stream>>>(q_in, Wq, bq, qW, 1);
    gemm_proj<<<gProj, 256, 0, stream>>>(k_in, Wk, bk, kW, 1);
    gemm_proj<<<gProj, 256, 0, stream>>>(v_in, Wv, bv, vW, 1);

    logits_mfma<<<dim3(16, 64, 16), 256, 0, stream>>>(qW, kW, rel, attn);
    softmax_k<<<8192, 256, 0, stream>>>(attn);
    pv_k<<<dim3(128, 16), 256, 0, stream>>>(attn, vW, mW);

    gemm_proj<<<gProj, 256, 0, stream>>>(mW, Wo, bo, out0, 0);
}

// Round 4
// 540.702 us; speedup vs baseline: 2.4441x; 1.5468x over previous
//
#include <hip/hip_runtime.h>

// B=2, S=2048, E=512, H=8, D=64, MAX_SEQ=2048
// out0: (2,2048,512) floats at d_out;  attn: (2,8,2048,2048) at d_out+2097152

typedef __attribute__((ext_vector_type(4))) float f32x4;
typedef __attribute__((ext_vector_type(8))) short short8;

__device__ inline unsigned short f2bf(float x) {             // RTN-even fp32->bf16
    unsigned u = __float_as_uint(x);
    unsigned r = (u + 0x7fffu + ((u >> 16) & 1u)) >> 16;
    return (unsigned short)r;
}
__device__ inline float bf2f(unsigned short h) {
    return __uint_as_float(((unsigned)h) << 16);
}
// LDS swizzle for [rows][64] bf16 tiles (128 B rows), 16B-granule XOR
__device__ inline int swz(int row, int bytecol) {
    return (row << 7) + (bytecol ^ ((row & 7) << 4));
}
__device__ inline void cvt4(float4 v, uint2& hi, uint2& lo) {
    unsigned short h0 = f2bf(v.x), h1 = f2bf(v.y), h2 = f2bf(v.z), h3 = f2bf(v.w);
    hi = make_uint2(((unsigned)h1 << 16) | h0, ((unsigned)h3 << 16) | h2);
    lo = make_uint2(((unsigned)f2bf(v.y - bf2f(h1)) << 16) | f2bf(v.x - bf2f(h0)),
                    ((unsigned)f2bf(v.w - bf2f(h3)) << 16) | f2bf(v.z - bf2f(h2)));
}

// ---------------------------------------------------------------------------
// K0: weight prep — W(512x512) -> WT hi/lo bf16 planes [n][k]
// ---------------------------------------------------------------------------
__global__ __launch_bounds__(256) void wt_prep(const float* __restrict__ W,
                                               unsigned short* __restrict__ WTh,
                                               unsigned short* __restrict__ WTl)
{
    __shared__ float Ls[32][33];
    const int t = threadIdx.x;
    const int k0 = blockIdx.x << 5, n0 = blockIdx.y << 5;
#pragma unroll
    for (int i = 0; i < 4; ++i) {
        int idx = (i << 8) + t;
        int kk = idx >> 5, nn = idx & 31;
        Ls[kk][nn] = W[(size_t)(k0 + kk) * 512 + n0 + nn];
    }
    __syncthreads();
#pragma unroll
    for (int i = 0; i < 2; ++i) {
        int idx = (i << 8) + t;
        int nn = idx >> 4, kp = idx & 15;
        float f0 = Ls[2 * kp][nn], f1 = Ls[2 * kp + 1][nn];
        unsigned short h0 = f2bf(f0), h1 = f2bf(f1);
        size_t off = (size_t)(n0 + nn) * 512 + k0 + 2 * kp;
        *(unsigned*)&WTh[off] = ((unsigned)h1 << 16) | h0;
        *(unsigned*)&WTl[off] = ((unsigned)f2bf(f1 - bf2f(h1)) << 16) | f2bf(f0 - bf2f(h0));
    }
}

// ---------------------------------------------------------------------------
// K1: C(4096x512) = A @ W + bias via split-bf16 MFMA (3 terms).
// layout 0: row-major; 1: BHSD (q,k); 2: BHDS transposed (v).
// ---------------------------------------------------------------------------
__global__ __launch_bounds__(256) void gemm_mfma(const float* __restrict__ A,
                                                 const unsigned short* __restrict__ WTh,
                                                 const unsigned short* __restrict__ WTl,
                                                 const float* __restrict__ bias,
                                                 float* __restrict__ out, int layout)
{
    __shared__ char smem[49152];
    char* aH = smem;            // [128][64] bf16 swz (16 KB)
    char* aL = smem + 16384;
    char* wH = smem + 32768;    // [64][64]  bf16 swz (8 KB)
    char* wL = smem + 40960;

    const int t = threadIdx.x;
    const int n0 = blockIdx.x << 6;
    const int m0 = blockIdx.y << 7;
    const int lane = t & 63, w = t >> 6;
    const int lr = lane & 15, kg = lane >> 4;

    f32x4 acc[2][4];
#pragma unroll
    for (int rf = 0; rf < 2; ++rf)
#pragma unroll
        for (int f = 0; f < 4; ++f) acc[rf][f] = {0.f, 0.f, 0.f, 0.f};

    for (int k0 = 0; k0 < 512; k0 += 64) {
        if (k0) __syncthreads();
        // stage A (128x64 fp32 -> hi/lo bf16)
#pragma unroll
        for (int i = 0; i < 8; ++i) {
            int idx = (i << 8) + t;
            int row = idx >> 4, c4 = idx & 15;
            float4 v = *(const float4*)&A[(size_t)(m0 + row) * 512 + k0 + (c4 << 2)];
            uint2 hi, lo; cvt4(v, hi, lo);
            int ph = swz(row, c4 << 3);
            *(uint2*)(aH + ph) = hi;
            *(uint2*)(aL + ph) = lo;
        }
        // stage WT planes (bf16 direct copy, 16B per thread-iter)
        // 2 planes x 64 rows x 8 uint4 = 1024 uint4 = 4 iters x 256 thr
#pragma unroll
        for (int i = 0; i < 4; ++i) {
            int idx = (i << 8) + t;
            int plane = idx >> 9, rem = idx & 511;
            int nn = rem >> 3, j8 = rem & 7;          // j8: 8-element (16B) granule
            const unsigned short* src = plane ? WTl : WTh;
            uint4 vv = *(const uint4*)&src[(size_t)(n0 + nn) * 512 + k0 + (j8 << 3)];
            *(uint4*)((plane ? wL : wH) + swz(nn, j8 << 4)) = vv;
        }
        __syncthreads();
#pragma unroll
        for (int kk = 0; kk < 2; ++kk) {
            int bc = (kk << 6) + (kg << 4);
            short8 b_h[4], b_l[4];
#pragma unroll
            for (int f = 0; f < 4; ++f) {
                b_h[f] = *(const short8*)(wH + swz((f << 4) + lr, bc));
                b_l[f] = *(const short8*)(wL + swz((f << 4) + lr, bc));
            }
#pragma unroll
            for (int rf = 0; rf < 2; ++rf) {
                int ar = (w << 5) + (rf << 4) + lr;
                short8 a_h = *(const short8*)(aH + swz(ar, bc));
                short8 a_l = *(const short8*)(aL + swz(ar, bc));
#pragma unroll
                for (int f = 0; f < 4; ++f) {
                    acc[rf][f] = __builtin_amdgcn_mfma_f32_16x16x32_bf16(a_h, b_h[f], acc[rf][f], 0, 0, 0);
                    acc[rf][f] = __builtin_amdgcn_mfma_f32_16x16x32_bf16(a_l, b_h[f], acc[rf][f], 0, 0, 0);
                    acc[rf][f] = __builtin_amdgcn_mfma_f32_16x16x32_bf16(a_h, b_l[f], acc[rf][f], 0, 0, 0);
                }
            }
        }
    }

#pragma unroll
    for (int rf = 0; rf < 2; ++rf) {
        int mbase = m0 + (w << 5) + (rf << 4) + (kg << 2);
#pragma unroll
        for (int f = 0; f < 4; ++f) {
            int n = n0 + (f << 4) + lr;
            float bv = bias[n];
            if (layout == 2) {
                int hh = n0 >> 6, d = (f << 4) + lr;
                int b = mbase >> 11, s = mbase & 2047;
                float4 vv = make_float4(acc[rf][f][0] + bv, acc[rf][f][1] + bv,
                                        acc[rf][f][2] + bv, acc[rf][f][3] + bv);
                *(float4*)&out[(size_t)(((b << 3) + hh) * 64 + d) * 2048 + s] = vv;
            } else {
#pragma unroll
                for (int e = 0; e < 4; ++e) {
                    int m = mbase + e;
                    float val = acc[rf][f][e] + bv;
                    if (layout == 0) {
                        out[(size_t)m * 512 + n] = val;
                    } else {
                        int b = m >> 11, s = m & 2047, hh = n0 >> 6, d = (f << 4) + lr;
                        out[(size_t)(((b << 3) + hh) * 2048 + s) * 64 + d] = val;
                    }
                }
            }
        }
    }
}

// ---------------------------------------------------------------------------
// K2: raw logits = QK^T (split-bf16, 3 MFMA terms) + masked rel (1 MFMA term)
// ---------------------------------------------------------------------------
__global__ __launch_bounds__(256) void logits_mfma(const float* __restrict__ q,
                                                   const float* __restrict__ k,
                                                   const float* __restrict__ rel,
                                                   float* __restrict__ attn)
{
    __shared__ char smem[61440];
    char* qh = smem;            // [32][64] bf16 hi, swizzled (4 KB)
    char* ql = smem + 4096;
    char* kh = smem + 8192;     // [128][64] bf16 hi (16 KB)
    char* kl = smem + 24576;
    char* rh = smem + 40960;    // [160][64] bf16 hi (20 KB)
    float* P = (float*)(smem + 8192);   // [32][162] fp32, overlays kh/kl after QK

    const int t  = threadIdx.x;
    const int j0 = blockIdx.x << 7;
    const int i0 = blockIdx.y << 5;
    const int bh = blockIdx.z;
    const bool anyRel = (j0 <= i0 + 31);
    const int m0 = 2016 + j0 - i0;

    {
        int row = t >> 3, d0 = (t & 7) << 3;
        const float* src = q + ((size_t)(bh * 2048 + i0 + row)) * 64 + d0;
#pragma unroll
        for (int i2 = 0; i2 < 2; ++i2) {
            float4 v = *(const float4*)(src + i2 * 4);
            uint2 hi, lo; cvt4(v, hi, lo);
            int phys = swz(row, (d0 + i2 * 4) * 2);
            *(uint2*)(qh + phys) = hi;
            *(uint2*)(ql + phys) = lo;
        }
    }
    {
        int row = t >> 1, d0 = (t & 1) << 5;
        const float* src = k + ((size_t)(bh * 2048 + j0 + row)) * 64 + d0;
#pragma unroll
        for (int i4 = 0; i4 < 8; ++i4) {
            float4 v = *(const float4*)(src + i4 * 4);
            uint2 hi, lo; cvt4(v, hi, lo);
            int phys = swz(row, (d0 + i4 * 4) * 2);
            *(uint2*)(kh + phys) = hi;
            *(uint2*)(kl + phys) = lo;
        }
    }
    if (anyRel) {
        int d0 = (t & 1) << 5;
        for (int rr = t >> 1; rr < 160; rr += 128) {
            int m = m0 + rr;
            if (m > 2047) m = 2047;
            const float* src = rel + m * 64 + d0;
#pragma unroll
            for (int i4 = 0; i4 < 8; ++i4) {
                float4 v = *(const float4*)(src + i4 * 4);
                unsigned short h0 = f2bf(v.x), h1 = f2bf(v.y), h2 = f2bf(v.z), h3 = f2bf(v.w);
                *(uint2*)(rh + swz(rr, (d0 + i4 * 4) * 2)) =
                    make_uint2(((unsigned)h1 << 16) | h0, ((unsigned)h3 << 16) | h2);
            }
        }
    }
    __syncthreads();

    const int lane = t & 63, w = t >> 6;
    const int wr = w >> 1, wc = w & 1;
    const int lr = lane & 15, kg = lane >> 4;

    short8 aH0 = *(const short8*)(qh + swz(16 * wr + lr, kg * 16));
    short8 aH1 = *(const short8*)(qh + swz(16 * wr + lr, 64 + kg * 16));
    short8 aL0 = *(const short8*)(ql + swz(16 * wr + lr, kg * 16));
    short8 aL1 = *(const short8*)(ql + swz(16 * wr + lr, 64 + kg * 16));

    f32x4 acc[4];
#pragma unroll
    for (int f = 0; f < 4; ++f) {
        int row = 64 * wc + 16 * f + lr;
        short8 bH0 = *(const short8*)(kh + swz(row, kg * 16));
        short8 bH1 = *(const short8*)(kh + swz(row, 64 + kg * 16));
        short8 bL0 = *(const short8*)(kl + swz(row, kg * 16));
        short8 bL1 = *(const short8*)(kl + swz(row, 64 + kg * 16));
        f32x4 c = {0.f, 0.f, 0.f, 0.f};
        c = __builtin_amdgcn_mfma_f32_16x16x32_bf16(aH0, bH0, c, 0, 0, 0);
        c = __builtin_amdgcn_mfma_f32_16x16x32_bf16(aH1, bH1, c, 0, 0, 0);
        c = __builtin_amdgcn_mfma_f32_16x16x32_bf16(aH0, bL0, c, 0, 0, 0);
        c = __builtin_amdgcn_mfma_f32_16x16x32_bf16(aH1, bL1, c, 0, 0, 0);
        c = __builtin_amdgcn_mfma_f32_16x16x32_bf16(aL0, bH0, c, 0, 0, 0);
        c = __builtin_amdgcn_mfma_f32_16x16x32_bf16(aL1, bH1, c, 0, 0, 0);
        acc[f] = c;
    }

    if (anyRel) {
        f32x4 pr[5];
#pragma unroll
        for (int ff = 0; ff < 5; ++ff) {
            int bandf = wc + 2 * ff;
            int row = 16 * bandf + lr;
            short8 rb0 = *(const short8*)(rh + swz(row, kg * 16));
            short8 rb1 = *(const short8*)(rh + swz(row, 64 + kg * 16));
            f32x4 c = {0.f, 0.f, 0.f, 0.f};
            c = __builtin_amdgcn_mfma_f32_16x16x32_bf16(aH0, rb0, c, 0, 0, 0);
            c = __builtin_amdgcn_mfma_f32_16x16x32_bf16(aH1, rb1, c, 0, 0, 0);
            pr[ff] = c;
        }
        __syncthreads();
#pragma unroll
        for (int ff = 0; ff < 5; ++ff) {
            int bandf = wc + 2 * ff;
#pragma unroll
            for (int e = 0; e < 4; ++e)
                P[(16 * wr + 4 * kg + e) * 162 + 16 * bandf + lr] = pr[ff][e];
        }
        __syncthreads();
    }

    const size_t obase = ((size_t)bh * 2048 + i0) * 2048 + j0;
#pragma unroll
    for (int f = 0; f < 4; ++f) {
        int cj = 64 * wc + 16 * f + lr;
#pragma unroll
        for (int e = 0; e < 4; ++e) {
            int r = 16 * wr + 4 * kg + e;
            float val = acc[f][e];
            if (anyRel && (j0 + cj) <= (i0 + r))
                val += P[r * 162 + cj + 31 - r];
            attn[obase + (size_t)r * 2048 + cj] = val;
        }
    }
}

// ---------------------------------------------------------------------------
// K3: per-row stats: m = max(raw), rZ = 1/sum exp((raw-m)/8). One wave/row.
// ---------------------------------------------------------------------------
__global__ __launch_bounds__(256) void stats_k(const float* __restrict__ attn,
                                               float2* __restrict__ stats)
{
    const int t    = threadIdx.x;
    const int lane = t & 63;
    const int w    = t >> 6;
    const int row  = (blockIdx.x << 2) + w;
    const float* p = attn + (size_t)row * 2048;

    float v[32];
#pragma unroll
    for (int c = 0; c < 8; ++c) {
        float4 x = *(const float4*)&p[(lane + (c << 6)) << 2];
        v[c * 4 + 0] = x.x; v[c * 4 + 1] = x.y; v[c * 4 + 2] = x.z; v[c * 4 + 3] = x.w;
    }
    float m = v[0];
#pragma unroll
    for (int i = 1; i < 32; ++i) m = fmaxf(m, v[i]);
#pragma unroll
    for (int off = 1; off < 64; off <<= 1) m = fmaxf(m, __shfl_xor(m, off, 64));

    float s = 0.f;
#pragma unroll
    for (int i = 0; i < 32; ++i) s += __expf((v[i] - m) * 0.125f);
#pragma unroll
    for (int off = 1; off < 64; off <<= 1) s += __shfl_xor(s, off, 64);

    if (lane == 0) stats[row] = make_float2(m, 1.0f / s);
}

// ---------------------------------------------------------------------------
// K4: fused normalize + attn write + PV MFMA.
// ---------------------------------------------------------------------------
__global__ __launch_bounds__(512) void pv_fused(float* __restrict__ attn,
                                                const float* __restrict__ vT,
                                                const float2* __restrict__ stats,
                                                float* __restrict__ merged)
{
    __shared__ char smem[50176];
    char* pH = smem;             // [128][64] bf16 swz (16 KB)
    char* pL = smem + 16384;
    char* vH = smem + 32768;     // [64][64]  bf16 swz (8 KB)
    char* vL = smem + 40960;
    float2* sm = (float2*)(smem + 49152);  // [128] row stats

    const int t = threadIdx.x;
    const int i0 = blockIdx.x << 7;
    const int bh = blockIdx.y;
    const int b = bh >> 3, h = bh & 7;
    const int lane = t & 63, w = t >> 6;
    const int lr = lane & 15, kg = lane >> 4;

    float* ab = attn + ((size_t)bh * 2048 + i0) * 2048;
    const float* vb = vT + (size_t)bh * 64 * 2048;

    if (t < 128) sm[t] = stats[bh * 2048 + i0 + t];
    __syncthreads();

    f32x4 acc[4];
#pragma unroll
    for (int f = 0; f < 4; ++f) acc[f] = {0.f, 0.f, 0.f, 0.f};

    for (int j0 = 0; j0 < 2048; j0 += 64) {
        if (j0) __syncthreads();
        // stage p: normalize, write back, convert hi/lo
#pragma unroll
        for (int i = 0; i < 4; ++i) {
            int idx = (i << 9) + t;
            int row = idx >> 4, c4 = idx & 15;
            size_t go = (size_t)row * 2048 + j0 + (c4 << 2);
            float4 x = *(const float4*)&ab[go];
            float2 s2 = sm[row];
            float4 p;
            p.x = __expf((x.x - s2.x) * 0.125f) * s2.y;
            p.y = __expf((x.y - s2.x) * 0.125f) * s2.y;
            p.z = __expf((x.z - s2.x) * 0.125f) * s2.y;
            p.w = __expf((x.w - s2.x) * 0.125f) * s2.y;
            *(float4*)&ab[go] = p;
            uint2 hi, lo; cvt4(p, hi, lo);
            int ph = swz(row, c4 << 3);
            *(uint2*)(pH + ph) = hi;
            *(uint2*)(pL + ph) = lo;
        }
        // stage v^T chunk (64 d x 64 j)
#pragma unroll
        for (int i = 0; i < 2; ++i) {
            int idx = (i << 9) + t;
            int d = idx >> 4, c4 = idx & 15;
            float4 x = *(const float4*)&vb[(size_t)d * 2048 + j0 + (c4 << 2)];
            uint2 hi, lo; cvt4(x, hi, lo);
            int ph = swz(d, c4 << 3);
            *(uint2*)(vH + ph) = hi;
            *(uint2*)(vL + ph) = lo;
        }
        __syncthreads();
#pragma unroll
        for (int kk = 0; kk < 2; ++kk) {
            int bc = (kk << 6) + (kg << 4);
            int ar = (w << 4) + lr;
            short8 a_h = *(const short8*)(pH + swz(ar, bc));
            short8 a_l = *(const short8*)(pL + swz(ar, bc));
#pragma unroll
            for (int f = 0; f < 4; ++f) {
                short8 b_h = *(const short8*)(vH + swz((f << 4) + lr, bc));
                short8 b_l = *(const short8*)(vL + swz((f << 4) + lr, bc));
                acc[f] = __builtin_amdgcn_mfma_f32_16x16x32_bf16(a_h, b_h, acc[f], 0, 0, 0);
                acc[f] = __builtin_amdgcn_mfma_f32_16x16x32_bf16(a_l, b_h, acc[f], 0, 0, 0);
                acc[f] = __builtin_amdgcn_mfma_f32_16x16x32_bf16(a_h, b_l, acc[f], 0, 0, 0);
            }
        }
    }
#pragma unroll
    for (int f = 0; f < 4; ++f) {
#pragma unroll
        for (int e = 0; e < 4; ++e) {
            int m = i0 + (w << 4) + (kg << 2) + e;
            merged[(size_t)((b << 11) + m) * 512 + (h << 6) + (f << 4) + lr] = acc[f][e];
        }
    }
}

// ---------------------------------------------------------------------------
extern "C" void kernel_launch(void* const* d_in, const int* in_sizes, int n_in,
                              void* d_out, int out_size, void* d_ws, size_t ws_size,
                              hipStream_t stream)
{
    const float* q_in = (const float*)d_in[0];
    const float* k_in = (const float*)d_in[1];
    const float* v_in = (const float*)d_in[2];
    const float* Wq   = (const float*)d_in[3];
    const float* bq   = (const float*)d_in[4];
    const float* Wk   = (const float*)d_in[5];
    const float* bk   = (const float*)d_in[6];
    const float* Wv   = (const float*)d_in[7];
    const float* bv   = (const float*)d_in[8];
    const float* Wo   = (const float*)d_in[9];
    const float* bo   = (const float*)d_in[10];
    const float* rel  = (const float*)d_in[11];

    float* out0 = (float*)d_out;
    float* attn = out0 + 2097152;

    float* ws = (float*)d_ws;
    float* qW = ws;                       // BHSD q; later reused as merged (mW)
    float* kW = ws + 2097152;             // BHSD k
    float* vT = ws + 4194304;             // BHDS v^T
    unsigned short* wt = (unsigned short*)(ws + 6291456);  // 8 planes x 262144
    float2* stats = (float2*)(ws + 7340032);               // 32768 rows

    dim3 gW(16, 16);
    wt_prep<<<gW, 256, 0, stream>>>(Wq, wt + 0 * 262144, wt + 1 * 262144);
    wt_prep<<<gW, 256, 0, stream>>>(Wk, wt + 2 * 262144, wt + 3 * 262144);
    wt_prep<<<gW, 256, 0, stream>>>(Wv, wt + 4 * 262144, wt + 5 * 262144);
    wt_prep<<<gW, 256, 0, stream>>>(Wo, wt + 6 * 262144, wt + 7 * 262144);

    dim3 gG(8, 32);
    gemm_mfma<<<gG, 256, 0, stream>>>(q_in, wt + 0 * 262144, wt + 1 * 262144, bq, qW, 1);
    gemm_mfma<<<gG, 256, 0, stream>>>(k_in, wt + 2 * 262144, wt + 3 * 262144, bk, kW, 1);
    gemm_mfma<<<gG, 256, 0, stream>>>(v_in, wt + 4 * 262144, wt + 5 * 262144, bv, vT, 2);

    logits_mfma<<<dim3(16, 64, 16), 256, 0, stream>>>(qW, kW, rel, attn);
    stats_k<<<8192, 256, 0, stream>>>(attn, stats);
    pv_fused<<<dim3(16, 16), 512, 0, stream>>>(attn, vT, stats, qW);

    gemm_mfma<<<gG, 256, 0, stream>>>(qW, wt + 6 * 262144, wt + 7 * 262144, bo, out0, 0);
}